// Round 9
// baseline (192.905 us; speedup 1.0000x reference)
//
#include <hip/hip_runtime.h>

constexpr int EMB  = 128;   // EMB_DIM
constexpr int H1D  = 256;   // 2*HIDDEN
constexpr int H2D  = 128;   // HIDDEN
constexpr int VOC  = 4096;  // VOCAB
constexpr int NSL  = 32;    // wsum slices (atomic-contention spreading)
constexpr int RPB  = 16;    // vocab rows per GEMM block

// ---------------- k_pre: embW1 = emb @ W1 (blocks 0..255);
//                  block 256: zero count/flagbits then xpos atomics;
//                  blocks 257..: zero cnt/needw/wagg/wsum/counters.
__global__ void k_pre(const float* __restrict__ emb, const float* __restrict__ W1,
                      float* __restrict__ embW1,
                      const int* __restrict__ xpos, int* count, unsigned int* flagbits,
                      int* cnt, unsigned int* needw, float* wagg, float* wsum,
                      int* nflag, int* total, int np, int n, int nwords) {
    int t = threadIdx.x;
    int b = blockIdx.x;
    if (b < VOC / RPB) {                       // ---- GEMM tile (proven body)
        __shared__ float er[RPB][EMB];         // 8 KB
        int r0 = b * RPB;
        for (int i = t; i < RPB * EMB; i += 256) {
            er[i / EMB][i % EMB] = emb[(size_t)r0 * EMB + i];
        }
        __syncthreads();
        float acc[RPB];
#pragma unroll
        for (int rr = 0; rr < RPB; rr++) acc[rr] = 0.0f;
        for (int k = 0; k < EMB; k++) {
            float w = W1[k * H1D + t];
#pragma unroll
            for (int rr = 0; rr < RPB; rr++) acc[rr] += er[rr][k] * w;
        }
#pragma unroll
        for (int rr = 0; rr < RPB; rr++) {
            embW1[(size_t)(r0 + rr) * H1D + t] = acc[rr];
        }
        return;
    }
    if (b == VOC / RPB) {                      // ---- xpos block: zero, sync, atomics
        for (int i = t; i < n; i += 256) count[i] = 0;
        for (int i = t; i < nwords; i += 256) flagbits[i] = 0u;
        __syncthreads();
        for (int p = t; p < np; p += 256) {
            int v = xpos[p];
            atomicAdd(&count[v], 1);
            atomicOr(&flagbits[v >> 5], 1u << (v & 31));
        }
        return;
    }
    int i = (b - (VOC / RPB + 1)) * 256 + t;   // ---- zero blocks
    if (i < n) { cnt[i] = 0; wagg[i] = 0.0f; }
    if (i < nwords) needw[i] = 0u;
    if (i < NSL * H1D) wsum[i] = 0.0f;
    if (i == 0) { *nflag = 0; *total = 0; }
}

// ---------------- in-degree histogram + needed-row mark (4 edges/thread).
__global__ void k_hist(const int* __restrict__ row, const int* __restrict__ col,
                       const unsigned int* __restrict__ flagbits, int* cnt,
                       unsigned int* markw, int ne) {
    int e = blockIdx.x * blockDim.x + threadIdx.x;
    int base = e * 4;
    if (base + 3 < ne) {
        int4 c4 = ((const int4*)col)[e];
        atomicAdd(&cnt[c4.x], 1);
        atomicAdd(&cnt[c4.y], 1);
        atomicAdd(&cnt[c4.z], 1);
        atomicAdd(&cnt[c4.w], 1);
        bool f0 = (flagbits[c4.x >> 5] >> (c4.x & 31)) & 1u;
        bool f1 = (flagbits[c4.y >> 5] >> (c4.y & 31)) & 1u;
        bool f2 = (flagbits[c4.z >> 5] >> (c4.z & 31)) & 1u;
        bool f3 = (flagbits[c4.w >> 5] >> (c4.w & 31)) & 1u;
        if (f0 | f1 | f2 | f3) {               // ~8% of threads
            int4 r4 = ((const int4*)row)[e];
            if (f0) atomicOr(&markw[r4.x >> 5], 1u << (r4.x & 31));
            if (f1) atomicOr(&markw[r4.y >> 5], 1u << (r4.y & 31));
            if (f2) atomicOr(&markw[r4.z >> 5], 1u << (r4.z & 31));
            if (f3) atomicOr(&markw[r4.w >> 5], 1u << (r4.w & 31));
        }
    } else {
        for (int q = base; q < ne; q++) {
            int c = col[q];
            atomicAdd(&cnt[c], 1);
            if ((flagbits[c >> 5] >> (c & 31)) & 1u) {
                int r = row[q];
                atomicOr(&markw[r >> 5], 1u << (r & 31));
            }
        }
    }
}

// ------- alloc: need = mark||flag; canonical needbits (ballot plain-store, race-free);
//         CSR bump-alloc (wave-aggregated); wagg self term; pk[v]={x[v],dinv[v]}.
__global__ void k_alloc(unsigned int* needw,
                        const unsigned int* __restrict__ flagbits,
                        const int* __restrict__ cnt, const int* __restrict__ count,
                        const int* __restrict__ x, int2* __restrict__ pk,
                        float* wagg, int* needlist, int* nflag, int* total,
                        int* offs, int* cursor, int n) {
    int v = blockIdx.x * blockDim.x + threadIdx.x;
    int lane = threadIdx.x & 63;
    int cv = 0;
    bool need = false;
    if (v < n) {
        cv = cnt[v];
        float dv = rsqrtf((float)cv + 1.0f);
        int2 p; p.x = x[v]; p.y = __float_as_int(dv);
        pk[v] = p;
        bool mark = (needw[v >> 5] >> (v & 31)) & 1u;
        bool flag = (flagbits[v >> 5] >> (v & 31)) & 1u;
        need = mark || flag;
        if (flag) wagg[v] = (float)count[v] / ((float)cv + 1.0f);  // count*dinv^2
    }
    unsigned long long nm = __ballot(need);
    int wbase = (v & ~63) >> 5;
    if (lane == 0)  needw[wbase]     = (unsigned int)(nm & 0xffffffffu);
    if (lane == 32) needw[wbase + 1] = (unsigned int)(nm >> 32);
    int seg = need ? cv : 0;
    int incl = seg;
#pragma unroll
    for (int d = 1; d < 64; d <<= 1) {
        int t = __shfl_up(incl, d);
        if (lane >= d) incl += t;
    }
    int excl = incl - seg;
    int wave_total = __shfl(incl, 63);
    int rank = __popcll(nm & ((1ull << lane) - 1));
    int wcnt = __popcll(nm);
    int base_id = 0, base_off = 0;
    if (lane == 0) {
        if (wcnt > 0) base_id = atomicAdd(nflag, wcnt);
        if (wave_total > 0) base_off = atomicAdd(total, wave_total);
    }
    base_id  = __shfl(base_id, 0);
    base_off = __shfl(base_off, 0);
    if (need) {
        needlist[base_id + rank] = v;
        int o = base_off + excl;
        offs[v] = o;
        cursor[v] = o;
    }
}

// ---------------- scatter (4 edges/thread, filtered via L1-resident bitmask):
//   one 8B pk gather per needed edge; wagg edge term for flagged cols (~2%).
__global__ void k_scatter(const int* __restrict__ row, const int* __restrict__ col,
                          const unsigned int* __restrict__ needw,
                          const unsigned int* __restrict__ flagbits,
                          const int* __restrict__ count,
                          const int2* __restrict__ pk,
                          int* cursor, int2* srowp, float* wagg, int ne) {
    int e = blockIdx.x * blockDim.x + threadIdx.x;
    int base = e * 4;
    auto doedge = [&](int c, int r) {
        if ((needw[c >> 5] >> (c & 31)) & 1u) {
            int pos = atomicAdd(&cursor[c], 1);
            int2 pr = pk[r];                    // {x[r], dinv[r]} — one 8B gather
            srowp[pos] = pr;
            if ((flagbits[c >> 5] >> (c & 31)) & 1u) {
                float dc = __int_as_float(pk[c].y);
                atomicAdd(&wagg[r], (float)count[c] * dc * __int_as_float(pr.y));
            }
        }
    };
    if (base + 3 < ne) {
        int4 c4 = ((const int4*)col)[e];
        int4 r4 = ((const int4*)row)[e];
        doedge(c4.x, r4.x);
        doedge(c4.y, r4.y);
        doedge(c4.z, r4.z);
        doedge(c4.w, r4.w);
    } else {
        for (int q = base; q < ne; q++) doedge(col[q], row[q]);
    }
}

// -------------------- fused conv1+conv2 over needed nodes (proven body):
__global__ void k_fconv(const int* __restrict__ needlist, const int* __restrict__ nneed_p,
                        const float* __restrict__ wagg, const int2* __restrict__ pk,
                        const int2* __restrict__ srowp,
                        const int* __restrict__ offs, const int* __restrict__ cnt,
                        const float* __restrict__ embW1, const float* __restrict__ b1,
                        float* __restrict__ wsum) {
    int lane = threadIdx.x & 63;
    int wib  = threadIdx.x >> 6;
    int wid  = blockIdx.x * (blockDim.x >> 6) + wib;
    int nw   = gridDim.x * (blockDim.x >> 6);
    int nn   = *nneed_p;
    const float4* __restrict__ ew = (const float4*)embW1;   // row r = ew + r*64
    float4 bfrag = ((const float4*)b1)[lane];
    float4 acc2 = {0.0f, 0.0f, 0.0f, 0.0f};

    for (int i = wid; i < nn; i += nw) {
        int v = needlist[i];
        int2 pv = pk[v];
        float dv = __int_as_float(pv.y);
        float wa = wagg[v];
        float4 s = ew[(size_t)pv.x * 64 + lane];
        float w0 = dv * dv;
        float4 acc;
        acc.x = bfrag.x + w0 * s.x;
        acc.y = bfrag.y + w0 * s.y;
        acc.z = bfrag.z + w0 * s.z;
        acc.w = bfrag.w + w0 * s.w;
        int start = offs[v], m = cnt[v];
        for (int base = 0; base < m; base += 64) {
            int mm = min(64, m - base);
            int xr = 0; float wr = 0.0f;
            if (lane < mm) {
                int2 pke = srowp[start + base + lane];
                xr = pke.x;
                wr = __int_as_float(pke.y) * dv;
            }
            int e = 0;
            for (; e + 4 <= mm; e += 4) {
                int i0 = __shfl(xr, e),     i1 = __shfl(xr, e + 1);
                int i2 = __shfl(xr, e + 2), i3 = __shfl(xr, e + 3);
                float q0 = __shfl(wr, e),     q1 = __shfl(wr, e + 1);
                float q2 = __shfl(wr, e + 2), q3 = __shfl(wr, e + 3);
                float4 t0 = ew[(size_t)i0 * 64 + lane];
                float4 t1 = ew[(size_t)i1 * 64 + lane];
                float4 t2 = ew[(size_t)i2 * 64 + lane];
                float4 t3 = ew[(size_t)i3 * 64 + lane];
                acc.x += q0 * t0.x + q1 * t1.x + q2 * t2.x + q3 * t3.x;
                acc.y += q0 * t0.y + q1 * t1.y + q2 * t2.y + q3 * t3.y;
                acc.z += q0 * t0.z + q1 * t1.z + q2 * t2.z + q3 * t3.z;
                acc.w += q0 * t0.w + q1 * t1.w + q2 * t2.w + q3 * t3.w;
            }
            for (; e < mm; e++) {
                int i0 = __shfl(xr, e);
                float q0 = __shfl(wr, e);
                float4 t0 = ew[(size_t)i0 * 64 + lane];
                acc.x += q0 * t0.x;
                acc.y += q0 * t0.y;
                acc.z += q0 * t0.z;
                acc.w += q0 * t0.w;
            }
        }
        acc2.x += wa * fmaxf(acc.x, 0.0f);
        acc2.y += wa * fmaxf(acc.y, 0.0f);
        acc2.z += wa * fmaxf(acc.z, 0.0f);
        acc2.w += wa * fmaxf(acc.w, 0.0f);
    }

    __shared__ float red[4][H1D];
    red[wib][4 * lane + 0] = acc2.x;
    red[wib][4 * lane + 1] = acc2.y;
    red[wib][4 * lane + 2] = acc2.z;
    red[wib][4 * lane + 3] = acc2.w;
    __syncthreads();
    int t = threadIdx.x;
    float ssum = red[0][t] + red[1][t] + red[2][t] + red[3][t];
    atomicAdd(&wsum[(blockIdx.x & (NSL - 1)) * H1D + t], ssum);
}

// ---------- fused head (proven): reduce slices; zmean = (wsum@W2)/NP + b2; out = zmean@Wc + bc
__global__ void k_zout(const float* __restrict__ wsum, const float* __restrict__ W2,
                       const float* __restrict__ b2, const float* __restrict__ Wc,
                       const float* __restrict__ bc, float* __restrict__ out,
                       float inv_np) {
    __shared__ float ws[H1D];
    __shared__ float z[H2D];
    int t = threadIdx.x;
    float s = 0.0f;
#pragma unroll
    for (int c = 0; c < NSL; c++) s += wsum[c * H1D + t];
    ws[t] = s;
    __syncthreads();
    if (t < H2D) {
        float acc = 0.0f;
#pragma unroll 8
        for (int k = 0; k < H1D; k++) acc += ws[k] * W2[k * H2D + t];
        z[t] = b2[t] + acc * inv_np;
    }
    __syncthreads();
    int c = blockIdx.x * blockDim.x + t;
    float acc = bc[c];
#pragma unroll 8
    for (int j = 0; j < H2D; j++) acc += z[j] * Wc[(size_t)j * VOC + c];
    out[c] = acc;
}

extern "C" void kernel_launch(void* const* d_in, const int* in_sizes, int n_in,
                              void* d_out, int out_size, void* d_ws, size_t ws_size,
                              hipStream_t stream) {
    const int n  = in_sizes[0];
    const int ne = in_sizes[1] / 2;
    const int np = in_sizes[2];

    const int*   x    = (const int*)d_in[0];
    const int*   ei   = (const int*)d_in[1];
    const int*   xpos = (const int*)d_in[2];
    const float* emb  = (const float*)d_in[3];
    const float* W1   = (const float*)d_in[4];
    const float* b1   = (const float*)d_in[5];
    const float* W2   = (const float*)d_in[6];
    const float* b2   = (const float*)d_in[7];
    const float* Wc   = (const float*)d_in[8];
    const float* bc   = (const float*)d_in[9];
    float*       out  = (float*)d_out;

    const int* row = ei;       // edge_index[0]
    const int* col = ei + ne;  // edge_index[1]

    char* p = (char*)d_ws;
    auto alloc = [&](size_t bytes) {
        char* r = p;
        p += (bytes + 255) & ~(size_t)255;
        return r;
    };
    const int nb     = (n + 255) / 256;
    const int nwords = nb * 8;   // padded so ballot stores stay in-bounds

    int*          cnt      = (int*)alloc((size_t)n * 4);
    int*          offs     = (int*)alloc((size_t)n * 4);
    int*          cursor   = (int*)alloc((size_t)n * 4);
    int*          count    = (int*)alloc((size_t)n * 4);
    int*          needlist = (int*)alloc((size_t)n * 4);
    unsigned int* needw    = (unsigned int*)alloc((size_t)nwords * 4);
    unsigned int* flagbits = (unsigned int*)alloc((size_t)nwords * 4);
    int2*         pk       = (int2*)alloc((size_t)n * 8);
    int2*         srowp    = (int2*)alloc((size_t)ne * 8);
    int*          nflag    = (int*)alloc(256 * 4);
    int*          total    = (int*)alloc(256 * 4);
    float*        wagg     = (float*)alloc((size_t)n * 4);
    float*        embW1    = (float*)alloc((size_t)VOC * H1D * 4);
    float*        wsum     = (float*)alloc((size_t)NSL * H1D * 4);

    const int ne4  = (ne + 3) / 4;
    const int neb4 = (ne4 + 255) / 256;

    k_pre<<<VOC / RPB + 1 + nb, 256, 0, stream>>>(emb, W1, embW1, xpos, count, flagbits,
                                                  cnt, needw, wagg, wsum, nflag, total,
                                                  np, n, nwords);
    k_hist<<<neb4, 256, 0, stream>>>(row, col, flagbits, cnt, needw, ne);
    k_alloc<<<nb, 256, 0, stream>>>(needw, flagbits, cnt, count, x, pk, wagg,
                                    needlist, nflag, total, offs, cursor, n);
    k_scatter<<<neb4, 256, 0, stream>>>(row, col, needw, flagbits, count, pk,
                                        cursor, srowp, wagg, ne);
    k_fconv<<<2048, 256, 0, stream>>>(needlist, nflag, wagg, pk, srowp, offs, cnt,
                                      embW1, b1, wsum);
    k_zout<<<VOC / 256, 256, 0, stream>>>(wsum, W2, b2, Wc, bc, out, 1.0f / (float)np);
}